// Round 1
// baseline (841.276 us; speedup 1.0000x reference)
//
#include <hip/hip_runtime.h>

#define D 32
#define THETA0 1.0f

__global__ void deg_kernel(const int* __restrict__ dst, float* __restrict__ deg, int n_edges) {
    int i = blockIdx.x * blockDim.x + threadIdx.x;
    if (i < n_edges) atomicAdd(&deg[dst[i]], 1.0f);
}

__global__ void dinv_kernel(const float* __restrict__ deg, float* __restrict__ dinv, int n_nodes) {
    int i = blockIdx.x * blockDim.x + threadIdx.x;
    if (i < n_nodes) {
        float d = deg[i];
        d = d < 1.0f ? 1.0f : d;
        dinv[i] = rsqrtf(d);
    }
}

// f = feat, h = theta0 * feat
__global__ void init_kernel(const float* __restrict__ feat, float* __restrict__ f,
                            float* __restrict__ h, int total) {
    int i = blockIdx.x * blockDim.x + threadIdx.x;
    if (i < total) {
        float v = feat[i];
        f[i] = v;
        h[i] = THETA0 * v;
    }
}

// one thread per (edge, feature): agg[dst][j] += f[src][j] * dinv[src]
__global__ void scatter_kernel(const int* __restrict__ src, const int* __restrict__ dst,
                               const float* __restrict__ f, const float* __restrict__ dinv,
                               float* __restrict__ agg, long long total) {
    long long t = (long long)blockIdx.x * blockDim.x + threadIdx.x;
    if (t >= total) return;
    int e = (int)(t >> 5);
    int j = (int)(t & 31);
    int s = src[e];
    int d = dst[e];
    float v = f[(size_t)s * D + j] * dinv[s];
    atomicAdd(&agg[(size_t)d * D + j], v);
}

// f = f - agg * dinv(row);  h += theta_k * f
__global__ void update_kernel(float* __restrict__ f, const float* __restrict__ agg,
                              const float* __restrict__ dinv, float* __restrict__ h,
                              float theta, int total) {
    int i = blockIdx.x * blockDim.x + threadIdx.x;
    if (i >= total) return;
    int row = i >> 5;  // D == 32
    float fn = f[i] - agg[i] * dinv[row];
    f[i] = fn;
    h[i] += theta * fn;
}

extern "C" void kernel_launch(void* const* d_in, const int* in_sizes, int n_in,
                              void* d_out, int out_size, void* d_ws, size_t ws_size,
                              hipStream_t stream) {
    const float* feat = (const float*)d_in[0];
    const int*   src  = (const int*)d_in[1];
    const int*   dst  = (const int*)d_in[2];
    float* h = (float*)d_out;

    int n_nodes = in_sizes[0] / D;
    int n_edges = in_sizes[1];
    long long total_nf = (long long)n_nodes * D;
    long long total_ef = (long long)n_edges * D;

    float* deg  = (float*)d_ws;                  // n_nodes
    float* dinv = deg  + n_nodes;                // n_nodes
    float* f    = dinv + n_nodes;                // n_nodes * D
    float* agg  = f    + total_nf;               // n_nodes * D

    const float theta[5] = {1.0f, -0.5f, 0.25f, -0.125f, 0.0625f};

    hipMemsetAsync(deg, 0, (size_t)n_nodes * sizeof(float), stream);
    deg_kernel<<<(n_edges + 255) / 256, 256, 0, stream>>>(dst, deg, n_edges);
    dinv_kernel<<<(n_nodes + 255) / 256, 256, 0, stream>>>(deg, dinv, n_nodes);
    init_kernel<<<(int)((total_nf + 255) / 256), 256, 0, stream>>>(feat, f, h, (int)total_nf);

    int scatter_blocks = (int)((total_ef + 255) / 256);
    for (int k = 1; k < 5; ++k) {
        hipMemsetAsync(agg, 0, (size_t)total_nf * sizeof(float), stream);
        scatter_kernel<<<scatter_blocks, 256, 0, stream>>>(src, dst, f, dinv, agg, total_ef);
        update_kernel<<<(int)((total_nf + 255) / 256), 256, 0, stream>>>(f, agg, dinv, h,
                                                                         theta[k], (int)total_nf);
    }
}

// Round 2
// 388.561 us; speedup vs baseline: 2.1651x; 2.1651x over previous
//
#include <hip/hip_runtime.h>

#define D 32
#define SCAN_BLK 256
#define SCAN_ITEMS 4   // 1024 elements per scan block

__global__ void deg_kernel(const int* __restrict__ dst, int* __restrict__ deg, int n_edges) {
    int i = blockIdx.x * blockDim.x + threadIdx.x;
    if (i < n_edges) atomicAdd(&deg[dst[i]], 1);
}

__global__ void dinv_kernel(const int* __restrict__ deg, float* __restrict__ dinv, int n) {
    int i = blockIdx.x * blockDim.x + threadIdx.x;
    if (i < n) {
        float d = (float)deg[i];
        dinv[i] = rsqrtf(d < 1.0f ? 1.0f : d);
    }
}

// block partial sums: 1024 deg values per block -> partial[b]
__global__ void scan_partial(const int* __restrict__ deg, int* __restrict__ partial, int n) {
    __shared__ int lds[SCAN_BLK];
    int base = blockIdx.x * (SCAN_BLK * SCAN_ITEMS) + threadIdx.x * SCAN_ITEMS;
    int s = 0;
    #pragma unroll
    for (int k = 0; k < SCAN_ITEMS; ++k) {
        int idx = base + k;
        s += (idx < n) ? deg[idx] : 0;
    }
    lds[threadIdx.x] = s;
    __syncthreads();
    for (int off = SCAN_BLK / 2; off > 0; off >>= 1) {
        if (threadIdx.x < off) lds[threadIdx.x] += lds[threadIdx.x + off];
        __syncthreads();
    }
    if (threadIdx.x == 0) partial[blockIdx.x] = lds[0];
}

// single-block exclusive scan of the partials (nb <= 256)
__global__ void scan_top(int* __restrict__ partial, int nb) {
    __shared__ int lds[SCAN_BLK];
    int tid = threadIdx.x;
    int v = (tid < nb) ? partial[tid] : 0;
    lds[tid] = v;
    __syncthreads();
    for (int off = 1; off < SCAN_BLK; off <<= 1) {
        int t = (tid >= off) ? lds[tid - off] : 0;
        __syncthreads();
        lds[tid] += t;
        __syncthreads();
    }
    if (tid < nb) partial[tid] = lds[tid] - v;  // exclusive
}

// final: row_ptr (and cursor copy) = global exclusive prefix sum of deg
__global__ void scan_final(const int* __restrict__ deg, const int* __restrict__ partial,
                           int* __restrict__ row_ptr, int* __restrict__ cursor, int n) {
    __shared__ int lds[SCAN_BLK];
    int tid = threadIdx.x;
    int base = blockIdx.x * (SCAN_BLK * SCAN_ITEMS) + tid * SCAN_ITEMS;
    int d[SCAN_ITEMS];
    int tsum = 0;
    #pragma unroll
    for (int k = 0; k < SCAN_ITEMS; ++k) {
        int idx = base + k;
        d[k] = (idx < n) ? deg[idx] : 0;
        tsum += d[k];
    }
    lds[tid] = tsum;
    __syncthreads();
    for (int off = 1; off < SCAN_BLK; off <<= 1) {
        int t = (tid >= off) ? lds[tid - off] : 0;
        __syncthreads();
        lds[tid] += t;
        __syncthreads();
    }
    int texcl = lds[tid] - tsum + partial[blockIdx.x];
    #pragma unroll
    for (int k = 0; k < SCAN_ITEMS; ++k) {
        int idx = base + k;
        if (idx < n) {
            row_ptr[idx] = texcl;
            cursor[idx] = texcl;
        }
        texcl += d[k];
    }
}

__global__ void fill_csr(const int* __restrict__ src, const int* __restrict__ dst,
                         int* __restrict__ cursor, int* __restrict__ csr_src, int n_edges) {
    int i = blockIdx.x * blockDim.x + threadIdx.x;
    if (i < n_edges) {
        int pos = atomicAdd(&cursor[dst[i]], 1);
        csr_src[pos] = src[i];
    }
}

// h = feat (theta0 == 1)
__global__ void init_h(const float* __restrict__ feat, float* __restrict__ h, int total4) {
    int i = blockIdx.x * blockDim.x + threadIdx.x;
    if (i < total4)
        reinterpret_cast<float4*>(h)[i] = reinterpret_cast<const float4*>(feat)[i];
}

// 8 lanes per node, each lane owns 4 features.
// agg = sum_{s in N(node)} f_cur[s] * dinv[s]
// f_next = f_cur[node] - agg * dinv[node];  h += theta * f_next
__global__ void hop_kernel(const int* __restrict__ row_ptr, const int* __restrict__ deg,
                           const int* __restrict__ csr_src, const float* __restrict__ dinv,
                           const float* __restrict__ f_cur, float* __restrict__ f_next,
                           float* __restrict__ h, float theta, int n_nodes) {
    int t = blockIdx.x * blockDim.x + threadIdx.x;
    int node = t >> 3;
    if (node >= n_nodes) return;
    int quad = (t & 7) << 2;
    int start = row_ptr[node];
    int cnt = deg[node];
    float ax = 0.f, ay = 0.f, az = 0.f, aw = 0.f;
    for (int e = 0; e < cnt; ++e) {
        int s = csr_src[start + e];
        float4 v = *reinterpret_cast<const float4*>(&f_cur[((size_t)s << 5) + quad]);
        float ds = dinv[s];
        ax = fmaf(v.x, ds, ax);
        ay = fmaf(v.y, ds, ay);
        az = fmaf(v.z, ds, az);
        aw = fmaf(v.w, ds, aw);
    }
    size_t off = ((size_t)node << 5) + quad;
    float dn = dinv[node];
    float4 fc = *reinterpret_cast<const float4*>(&f_cur[off]);
    float4 fn;
    fn.x = fc.x - ax * dn;
    fn.y = fc.y - ay * dn;
    fn.z = fc.z - az * dn;
    fn.w = fc.w - aw * dn;
    *reinterpret_cast<float4*>(&f_next[off]) = fn;
    float4 hv = *reinterpret_cast<const float4*>(&h[off]);
    hv.x = fmaf(theta, fn.x, hv.x);
    hv.y = fmaf(theta, fn.y, hv.y);
    hv.z = fmaf(theta, fn.z, hv.z);
    hv.w = fmaf(theta, fn.w, hv.w);
    *reinterpret_cast<float4*>(&h[off]) = hv;
}

extern "C" void kernel_launch(void* const* d_in, const int* in_sizes, int n_in,
                              void* d_out, int out_size, void* d_ws, size_t ws_size,
                              hipStream_t stream) {
    const float* feat = (const float*)d_in[0];
    const int*   src  = (const int*)d_in[1];
    const int*   dst  = (const int*)d_in[2];
    float* h = (float*)d_out;

    int n_nodes = in_sizes[0] / D;
    int n_edges = in_sizes[1];
    long long total_nf = (long long)n_nodes * D;

    // workspace layout
    int*   deg     = (int*)d_ws;                   // n_nodes
    int*   row_ptr = deg + n_nodes;                // n_nodes
    int*   cursor  = row_ptr + n_nodes;            // n_nodes
    int*   partial = cursor + n_nodes;             // <= 256
    int*   csr_src = partial + 256;                // n_edges
    float* dinv    = (float*)(csr_src + n_edges);  // n_nodes
    float* f1      = dinv + n_nodes;               // n_nodes * D
    float* f2      = f1 + total_nf;                // n_nodes * D

    const float theta[5] = {1.0f, -0.5f, 0.25f, -0.125f, 0.0625f};

    hipMemsetAsync(deg, 0, (size_t)n_nodes * sizeof(int), stream);
    deg_kernel<<<(n_edges + 255) / 256, 256, 0, stream>>>(dst, deg, n_edges);
    dinv_kernel<<<(n_nodes + 255) / 256, 256, 0, stream>>>(deg, dinv, n_nodes);

    int nb = (n_nodes + SCAN_BLK * SCAN_ITEMS - 1) / (SCAN_BLK * SCAN_ITEMS);  // 98 for 100K
    scan_partial<<<nb, SCAN_BLK, 0, stream>>>(deg, partial, n_nodes);
    scan_top<<<1, SCAN_BLK, 0, stream>>>(partial, nb);
    scan_final<<<nb, SCAN_BLK, 0, stream>>>(deg, partial, row_ptr, cursor, n_nodes);
    fill_csr<<<(n_edges + 255) / 256, 256, 0, stream>>>(src, dst, cursor, csr_src, n_edges);

    int total4 = (int)(total_nf / 4);
    init_h<<<(total4 + 255) / 256, 256, 0, stream>>>(feat, h, total4);

    int hop_threads = n_nodes * 8;
    int hop_blocks = (hop_threads + 255) / 256;
    const float* cur = feat;
    float* nxt = f1;
    float* other = f2;
    for (int k = 1; k < 5; ++k) {
        hop_kernel<<<hop_blocks, 256, 0, stream>>>(row_ptr, deg, csr_src, dinv,
                                                   cur, nxt, h, theta[k], n_nodes);
        const float* old_cur = cur;
        cur = nxt;
        nxt = (k == 1) ? other : (float*)old_cur;
    }
}